// Round 25
// baseline (285.444 us; speedup 1.0000x reference)
//
#include <hip/hip_runtime.h>

// GCN forward, MI355X. v25 — v24 (283.4us) with RQH 4->8 on the CSR chunk
// kernels: LDS 25->12.5KB, k_hist3 512->1024 blocks (4/CU), k_fill3
// 256->512 (2/CU; was exactly 1/CU with no slack). Sibling quarter-blocks
// share a chunk's edge stream -> redundant reads are L2-hits.
// Everything else byte-identical to v24.

#define N_NODES 50000
#define N_EDGES 800000
#define D 128
#define NSH 8
#define PROWS (N_NODES + 8)
#define PANEL ((size_t)PROWS * 16)
#define NC 64
#define CSZ (N_EDGES / NC)
#define NW (N_NODES / 2)
#define RQH 8
#define NWQ (NW / RQH)              // 3125 words = 6250 nodes per quarter
#define CS_CAP (N_EDGES + 8 * N_NODES)
#define TROWS 80

// ---------------- CSR build (no global atomics) ----------------

__global__ __launch_bounds__(512) void k_hist3(const int* __restrict__ src, const int* __restrict__ dst,
                                               unsigned* __restrict__ ghd16, unsigned* __restrict__ ghs16) {
    __shared__ unsigned h[NWQ];         // 12.5 KB
    const int rq  = blockIdx.x & (RQH - 1);
    const int arr = (blockIdx.x >> 3) & 1;
    const int c   = blockIdx.x >> 4;
    const int wbase = rq * NWQ;
    const int nbase = wbase * 2;
    const int t = threadIdx.x;
    for (int i = t; i < NWQ; i += 512) h[i] = 0u;
    __syncthreads();
    const int* __restrict__ col = arr ? src : dst;
    const int e0 = c * CSZ, e1 = e0 + CSZ;
    for (int e = e0 + t; e < e1; e += 512) {
        unsigned loc = (unsigned)(col[e] - nbase);
        if (loc < 2u * NWQ) atomicAdd(&h[loc >> 1], 1u << ((loc & 1) << 4));
    }
    __syncthreads();
    unsigned* __restrict__ outp = (arr ? ghs16 : ghd16) + (size_t)c * NW + wbase;
    for (int i = t; i < NWQ; i += 512) outp[i] = h[i];
}

__global__ __launch_bounds__(256) void k_merge3(unsigned* __restrict__ ghd16, const unsigned* __restrict__ ghs16,
                                                int* __restrict__ rowcnt, int* __restrict__ rowtrue,
                                                float* __restrict__ dinv) {
    int w = blockIdx.x * 256 + threadIdx.x;
    if (w >= NW) return;
    unsigned runlo = 0, runhi = 0;
#pragma unroll
    for (int c = 0; c < NC; c++) {
        unsigned v = ghd16[(size_t)c * NW + w];
        ghd16[(size_t)c * NW + w] = runlo | (runhi << 16);
        runlo += v & 0xffffu; runhi += v >> 16;
    }
    rowtrue[2 * w]     = (int)runlo;
    rowtrue[2 * w + 1] = (int)runhi;
    rowcnt[2 * w]      = (int)((runlo + 7u) & ~7u);
    rowcnt[2 * w + 1]  = (int)((runhi + 7u) & ~7u);
    unsigned dlo = 0, dhi = 0;
#pragma unroll
    for (int c = 0; c < NC; c++) {
        unsigned v = ghs16[(size_t)c * NW + w];
        dlo += v & 0xffffu; dhi += v >> 16;
    }
    dinv[2 * w]     = 1.0f / (float)(dlo > 1u ? dlo : 1u);
    dinv[2 * w + 1] = 1.0f / (float)(dhi > 1u ? dhi : 1u);
}

__global__ __launch_bounds__(1024) void k_scan1(const int* __restrict__ cnt, int* __restrict__ excl,
                                                int* __restrict__ blocksum, int n) {
    __shared__ int wsum[16];
    int i = blockIdx.x * 1024 + threadIdx.x;
    int v = (i < n) ? cnt[i] : 0;
    int lane = threadIdx.x & 63, wid = threadIdx.x >> 6;
    int x = v;
#pragma unroll
    for (int off = 1; off < 64; off <<= 1) {
        int y = __shfl_up(x, off, 64);
        if (lane >= off) x += y;
    }
    if (lane == 63) wsum[wid] = x;
    __syncthreads();
    if (threadIdx.x == 0) {
        int run = 0;
        for (int w = 0; w < 16; w++) { int t = wsum[w]; wsum[w] = run; run += t; }
        blocksum[blockIdx.x] = run;
    }
    __syncthreads();
    if (i < n) excl[i] = (x - v) + wsum[wid];
}

__global__ void k_scan2(const int* __restrict__ blocksum, int* __restrict__ blockoff,
                        int* __restrict__ rowptr_last, int nblk) {
    if (threadIdx.x == 0) {
        int run = 0;
        for (int b = 0; b < nblk; b++) { int t = blocksum[b]; blockoff[b] = run; run += t; }
        rowptr_last[0] = run;
    }
}

__global__ __launch_bounds__(1024) void k_scan3(int* __restrict__ excl, const int* __restrict__ blockoff, int n) {
    int i = blockIdx.x * 1024 + threadIdx.x;
    if (i < n) excl[i] += blockoff[blockIdx.x];
}

__global__ __launch_bounds__(512) void k_fill3(const int* __restrict__ src, const int* __restrict__ dst,
                                               const int* __restrict__ rowptr, const unsigned* __restrict__ ghd16,
                                               unsigned short* __restrict__ cs16) {
    __shared__ unsigned cnt[NWQ];       // 12.5 KB
    const int rq = blockIdx.x & (RQH - 1);
    const int c  = blockIdx.x >> 3;
    const int nbase = rq * NWQ * 2;
    const int t = threadIdx.x;
    for (int i = t; i < NWQ; i += 512) cnt[i] = 0u;
    __syncthreads();
    const unsigned* __restrict__ basep = ghd16 + (size_t)c * NW;
    const int e0 = c * CSZ, e1 = e0 + CSZ;
    for (int e = e0 + t; e < e1; e += 512) {
        int d = dst[e];
        unsigned loc = (unsigned)(d - nbase);
        if (loc < 2u * NWQ) {
            int sh = (loc & 1) << 4;
            unsigned old = atomicAdd(&cnt[loc >> 1], 1u << sh);
            int p = (int)((old >> sh) & 0xffffu);
            int base = (int)((basep[d >> 1] >> ((d & 1) << 4)) & 0xffffu);
            cs16[rowptr[d] + base + p] = (unsigned short)src[e];
        }
    }
}

__global__ __launch_bounds__(256) void k_pad(const int* __restrict__ rowptr, const int* __restrict__ rowtrue,
                                             unsigned short* __restrict__ cs16,
                                             float* __restrict__ bufA, float* __restrict__ bufB) {
    int n = blockIdx.x * 256 + threadIdx.x;
    if (n < N_NODES) {
        int e0 = rowptr[n] + rowtrue[n], e1 = rowptr[n + 1];
        for (int e = e0; e < e1; e++) cs16[e] = (unsigned short)N_NODES;
    }
    if (blockIdx.x == 0) {
        int t = threadIdx.x;
        float* b = (t & 128) ? bufB : bufA;
        int p = (t >> 4) & 7, cc = t & 15;
        b[(size_t)p * PANEL + (size_t)N_NODES * 16 + cc] = 0.f;
    }
}

// ---------------- panelize ----------------

__global__ __launch_bounds__(256) void k_panelize(const float* __restrict__ in, const float* __restrict__ dinv,
                                                  float* __restrict__ outp) {
    int tid = blockIdx.x * 256 + threadIdx.x;
    if (tid >= N_NODES * 32) return;
    int p = tid / (N_NODES * 4);
    int r = tid - p * (N_NODES * 4);
    int node = r >> 2, qq = r & 3;
    float w = dinv[node];
    float4 v = *reinterpret_cast<const float4*>(&in[(size_t)node * D + p * 16 + qq * 4]);
    v.x *= w; v.y *= w; v.z *= w; v.w *= w;
    *reinterpret_cast<float4*>(&outp[(size_t)p * PANEL + (size_t)node * 16 + qq * 4]) = v;
}

// ---------------- SpMM aggregation (v16 proven: natural order) ----------------

__global__ __launch_bounds__(256) void k_agg(const float* __restrict__ hp,
                                             const int* __restrict__ rp, const unsigned short* __restrict__ cs16,
                                             float* __restrict__ outp) {
    const int l4 = threadIdx.x & 3;
    const int grp = threadIdx.x >> 2;
    const int slice = blockIdx.x & (NSH - 1);
    const int node = (blockIdx.x >> 3) * 64 + grp;
    if (node >= N_NODES) return;
    const float* __restrict__ pan = hp + (size_t)slice * PANEL + l4 * 4;
    int s0 = rp[node], s1 = rp[node + 1];
    float4 acc = {0.f, 0.f, 0.f, 0.f};
    for (int e = s0; e < s1; e += 8) {
        int4 r = *reinterpret_cast<const int4*>(&cs16[e]);
        int i0 = r.x & 0xffff, i1 = (r.x >> 16) & 0xffff;
        int i2 = r.y & 0xffff, i3 = (r.y >> 16) & 0xffff;
        int i4 = r.z & 0xffff, i5 = (r.z >> 16) & 0xffff;
        int i6 = r.w & 0xffff, i7 = (r.w >> 16) & 0xffff;
        float4 a0 = *reinterpret_cast<const float4*>(&pan[(size_t)i0 * 16]);
        float4 a1 = *reinterpret_cast<const float4*>(&pan[(size_t)i1 * 16]);
        float4 a2 = *reinterpret_cast<const float4*>(&pan[(size_t)i2 * 16]);
        float4 a3 = *reinterpret_cast<const float4*>(&pan[(size_t)i3 * 16]);
        float4 a4 = *reinterpret_cast<const float4*>(&pan[(size_t)i4 * 16]);
        float4 a5 = *reinterpret_cast<const float4*>(&pan[(size_t)i5 * 16]);
        float4 a6 = *reinterpret_cast<const float4*>(&pan[(size_t)i6 * 16]);
        float4 a7 = *reinterpret_cast<const float4*>(&pan[(size_t)i7 * 16]);
        acc.x += ((a0.x + a1.x) + (a2.x + a3.x)) + ((a4.x + a5.x) + (a6.x + a7.x));
        acc.y += ((a0.y + a1.y) + (a2.y + a3.y)) + ((a4.y + a5.y) + (a6.y + a7.y));
        acc.z += ((a0.z + a1.z) + (a2.z + a3.z)) + ((a4.z + a5.z) + (a6.z + a7.z));
        acc.w += ((a0.w + a1.w) + (a2.w + a3.w)) + ((a4.w + a5.w) + (a6.w + a7.w));
    }
    *reinterpret_cast<float4*>(&outp[(size_t)slice * PANEL + (size_t)node * 16 + l4 * 4]) = acc;
}

// ---------------- dense layer (v18/v19 proven: 80x128, 52KB, grid 625) ----------------

__global__ __launch_bounds__(256, 3) void k_gemm(const float* __restrict__ in, const float* __restrict__ W,
                                                 const float* __restrict__ bias, float* __restrict__ out,
                                                 int nrows, int relu,
                                                 const float* __restrict__ dscale,
                                                 const float* __restrict__ pw, const float* __restrict__ pb,
                                                 float* __restrict__ pi_out, float* __restrict__ colsum) {
    __shared__ float wl[64 * D];     // 32 KB: current W k-half
    __shared__ float at[64 * TROWS]; // 20 KB
    int t = threadIdx.x;
    const int head = (pw != nullptr);
    const int tx = t & 15;
    const int ro = t >> 4;
    const int row0 = blockIdx.x * TROWS;
    float4 bv1 = reinterpret_cast<const float4*>(bias)[tx];
    float4 bv2 = reinterpret_cast<const float4*>(bias)[16 + tx];
    float4 pw1 = head ? reinterpret_cast<const float4*>(pw)[tx]      : float4{0, 0, 0, 0};
    float4 pw2 = head ? reinterpret_cast<const float4*>(pw)[16 + tx] : float4{0, 0, 0, 0};
    float pb0 = head ? pb[0] : 0.f;
    float4 cs1 = {0, 0, 0, 0}, cs2 = {0, 0, 0, 0};

    int sidx[5], skb[5];
#pragma unroll
    for (int j = 0; j < 5; j++) {
        int i = t + j * 256;
        int r = i % TROWS;
        int pq = i / TROWS;
        sidx[j] = r;
        skb[j] = (pq & 3) * 4 + (pq >> 2) * 16;
    }

#define LOADA(va, h)                                                                   \
    _Pragma("unroll")                                                                  \
    for (int j = 0; j < 5; j++) {                                                      \
        int i = t + j * 256;                                                           \
        int pq = i / TROWS;                                                            \
        int p = (h) * 4 + (pq >> 2);                                                   \
        int c4 = pq & 3;                                                               \
        va[j] = *reinterpret_cast<const float4*>(                                      \
            &in[(size_t)p * PANEL + (size_t)(row0 + sidx[j]) * 16 + c4 * 4]);          \
    }

#define WRITEA(va)                                                                     \
    _Pragma("unroll")                                                                  \
    for (int j = 0; j < 5; j++) {                                                      \
        int kb = skb[j], r = sidx[j];                                                  \
        at[(kb + 0) * TROWS + r] = va[j].x; at[(kb + 1) * TROWS + r] = va[j].y;        \
        at[(kb + 2) * TROWS + r] = va[j].z; at[(kb + 3) * TROWS + r] = va[j].w;        \
    }

#define STAGEW(h)                                                                      \
    _Pragma("unroll")                                                                  \
    for (int j = 0; j < 8; j++) {                                                      \
        int i = t + j * 256;                                                           \
        reinterpret_cast<float4*>(wl)[i] =                                             \
            reinterpret_cast<const float4*>(W + (h) * 64 * D)[i];                      \
    }

#define KLOOP                                                                          \
    _Pragma("unroll 4")                                                                \
    for (int kk = 0; kk < 64; kk++) {                                                  \
        float4 a  = *reinterpret_cast<const float4*>(&at[kk * TROWS + ro * 5]);        \
        float  a4 = at[kk * TROWS + ro * 5 + 4];                                       \
        float4 w1 = *reinterpret_cast<const float4*>(&wl[kk * D + tx * 4]);            \
        float4 w2 = *reinterpret_cast<const float4*>(&wl[kk * D + 64 + tx * 4]);       \
        acc[0][0] += a.x * w1.x; acc[0][1] += a.x * w1.y; acc[0][2] += a.x * w1.z; acc[0][3] += a.x * w1.w; \
        acc[0][4] += a.x * w2.x; acc[0][5] += a.x * w2.y; acc[0][6] += a.x * w2.z; acc[0][7] += a.x * w2.w; \
        acc[1][0] += a.y * w1.x; acc[1][1] += a.y * w1.y; acc[1][2] += a.y * w1.z; acc[1][3] += a.y * w1.w; \
        acc[1][4] += a.y * w2.x; acc[1][5] += a.y * w2.y; acc[1][6] += a.y * w2.z; acc[1][7] += a.y * w2.w; \
        acc[2][0] += a.z * w1.x; acc[2][1] += a.z * w1.y; acc[2][2] += a.z * w1.z; acc[2][3] += a.z * w1.w; \
        acc[2][4] += a.z * w2.x; acc[2][5] += a.z * w2.y; acc[2][6] += a.z * w2.z; acc[2][7] += a.z * w2.w; \
        acc[3][0] += a.w * w1.x; acc[3][1] += a.w * w1.y; acc[3][2] += a.w * w1.z; acc[3][3] += a.w * w1.w; \
        acc[3][4] += a.w * w2.x; acc[3][5] += a.w * w2.y; acc[3][6] += a.w * w2.z; acc[3][7] += a.w * w2.w; \
        acc[4][0] += a4 * w1.x; acc[4][1] += a4 * w1.y; acc[4][2] += a4 * w1.z; acc[4][3] += a4 * w1.w;     \
        acc[4][4] += a4 * w2.x; acc[4][5] += a4 * w2.y; acc[4][6] += a4 * w2.z; acc[4][7] += a4 * w2.w;     \
    }

    float acc[5][8];
#pragma unroll
    for (int j = 0; j < 5; j++)
#pragma unroll
        for (int c = 0; c < 8; c++) acc[j][c] = 0.f;

    float4 va[5];
    LOADA(va, 0);
    STAGEW(0);
    WRITEA(va);
    __syncthreads();
    LOADA(va, 1);
    KLOOP;
    __syncthreads();
    WRITEA(va);
    STAGEW(1);
    __syncthreads();
    KLOOP;

#pragma unroll
    for (int j = 0; j < 5; j++) {
        int gr = row0 + ro * 5 + j;
        float4 o1, o2;
        o1.x = acc[j][0] + bv1.x; o1.y = acc[j][1] + bv1.y;
        o1.z = acc[j][2] + bv1.z; o1.w = acc[j][3] + bv1.w;
        o2.x = acc[j][4] + bv2.x; o2.y = acc[j][5] + bv2.y;
        o2.z = acc[j][6] + bv2.z; o2.w = acc[j][7] + bv2.w;
        if (relu) {
            o1.x = fmaxf(o1.x, 0.f); o1.y = fmaxf(o1.y, 0.f);
            o1.z = fmaxf(o1.z, 0.f); o1.w = fmaxf(o1.w, 0.f);
            o2.x = fmaxf(o2.x, 0.f); o2.y = fmaxf(o2.y, 0.f);
            o2.z = fmaxf(o2.z, 0.f); o2.w = fmaxf(o2.w, 0.f);
        }
        if (head) {
            cs1.x += o1.x; cs1.y += o1.y; cs1.z += o1.z; cs1.w += o1.w;
            cs2.x += o2.x; cs2.y += o2.y; cs2.z += o2.z; cs2.w += o2.w;
            float pr = o1.x * pw1.x + o1.y * pw1.y + o1.z * pw1.z + o1.w * pw1.w
                     + o2.x * pw2.x + o2.y * pw2.y + o2.z * pw2.z + o2.w * pw2.w;
#pragma unroll
            for (int m = 8; m > 0; m >>= 1) pr += __shfl_xor(pr, m, 16);
            if (tx == 0) pi_out[gr] = pr + pb0;
        } else {
            if (dscale) {
                float w = dscale[gr];
                o1.x *= w; o1.y *= w; o1.z *= w; o1.w *= w;
                o2.x *= w; o2.y *= w; o2.z *= w; o2.w *= w;
            }
            size_t base1 = (size_t)(tx >> 2) * PANEL + (size_t)gr * 16 + (tx & 3) * 4;
            *reinterpret_cast<float4*>(&out[base1]) = o1;
            *reinterpret_cast<float4*>(&out[base1 + 4 * PANEL]) = o2;
        }
    }

    if (head) {
        __syncthreads();
        float* csl = at;
        if (t < D) csl[t] = 0.f;
        __syncthreads();
        atomicAdd(&csl[tx * 4 + 0], cs1.x);
        atomicAdd(&csl[tx * 4 + 1], cs1.y);
        atomicAdd(&csl[tx * 4 + 2], cs1.z);
        atomicAdd(&csl[tx * 4 + 3], cs1.w);
        atomicAdd(&csl[64 + tx * 4 + 0], cs2.x);
        atomicAdd(&csl[64 + tx * 4 + 1], cs2.y);
        atomicAdd(&csl[64 + tx * 4 + 2], cs2.z);
        atomicAdd(&csl[64 + tx * 4 + 3], cs2.w);
        __syncthreads();
        if (t < D) atomicAdd(&colsum[t], csl[t]);
    }
#undef LOADA
#undef WRITEA
#undef STAGEW
#undef KLOOP
}

// ---------------- value head ----------------

__global__ __launch_bounds__(128) void k_value(const float* __restrict__ colsum, const float* __restrict__ vw,
                                               const float* __restrict__ vb, float* __restrict__ out) {
    __shared__ float red[128];
    int t = threadIdx.x;
    red[t] = (colsum[t] * (1.0f / (float)N_NODES)) * vw[t];
    __syncthreads();
    for (int s = 64; s > 0; s >>= 1) {
        if (t < s) red[t] += red[t + s];
        __syncthreads();
    }
    if (t == 0) out[0] = red[0] + vb[0];
}

__global__ __launch_bounds__(64) void k_ws_too_small(float* __restrict__ out, int n) {
    int i = blockIdx.x * 64 + threadIdx.x;
    if (i < n) out[i] = -1e30f;
}

// ---------------- launch ----------------

extern "C" void kernel_launch(void* const* d_in, const int* in_sizes, int n_in,
                              void* d_out, int out_size, void* d_ws, size_t ws_size,
                              hipStream_t stream) {
    const float* features = (const float*)d_in[0];
    const int*   src      = (const int*)d_in[1];
    const int*   dst      = (const int*)d_in[2];
    const float* W1 = (const float*)d_in[3];
    const float* b1 = (const float*)d_in[4];
    const float* W2 = (const float*)d_in[5];
    const float* b2 = (const float*)d_in[6];
    const float* W3 = (const float*)d_in[7];
    const float* b3 = (const float*)d_in[8];
    const float* pw = (const float*)d_in[9];
    const float* pb = (const float*)d_in[10];
    const float* vw = (const float*)d_in[11];
    const float* vb = (const float*)d_in[12];
    float* out = (float*)d_out;

    char* ws = (char*)d_ws;
    size_t off = 0;
    auto alloc = [&](size_t bytes) -> char* {
        char* p = ws + off;
        off += (bytes + 255) & ~(size_t)255;
        return p;
    };
    float* dinv     = (float*)alloc((size_t)N_NODES * 4);
    int*   rowptr   = (int*)alloc((size_t)(N_NODES + 1) * 4);
    int*   rowcnt   = (int*)alloc((size_t)N_NODES * 4);
    int*   rowtrue  = (int*)alloc((size_t)N_NODES * 4);
    int*   blocksum = (int*)alloc(64 * 4);
    int*   blockoff = (int*)alloc(64 * 4);
    float* colsum   = (float*)alloc(D * 4);
    unsigned short* cs16 = (unsigned short*)alloc((size_t)CS_CAP * 2);
    float* bufA     = (float*)alloc((size_t)NSH * PANEL * 4);
    float* bufB     = (float*)alloc((size_t)NSH * PANEL * 4);

    unsigned* ghd16 = (unsigned*)bufB;
    unsigned* ghs16 = ghd16 + (size_t)NC * NW;

    if (off > ws_size) {
        k_ws_too_small<<<(out_size + 63) / 64, 64, 0, stream>>>(out, out_size);
        return;
    }

    hipMemsetAsync(colsum, 0, (size_t)D * 4, stream);

    k_hist3<<<NC * 2 * RQH, 512, 0, stream>>>(src, dst, ghd16, ghs16);
    k_merge3<<<(NW + 255) / 256, 256, 0, stream>>>(ghd16, ghs16, rowcnt, rowtrue, dinv);

    int nblk = (N_NODES + 1023) / 1024;
    k_scan1<<<nblk, 1024, 0, stream>>>(rowcnt, rowptr, blocksum, N_NODES);
    k_scan2<<<1, 64, 0, stream>>>(blocksum, blockoff, rowptr + N_NODES, nblk);
    k_scan3<<<nblk, 1024, 0, stream>>>(rowptr, blockoff, N_NODES);
    k_fill3<<<NC * RQH, 512, 0, stream>>>(src, dst, rowptr, ghd16, cs16);
    k_pad<<<(N_NODES + 255) / 256, 256, 0, stream>>>(rowptr, rowtrue, cs16, bufA, bufB);

    k_panelize<<<(N_NODES * 32 + 255) / 256, 256, 0, stream>>>(features, dinv, bufA);

    int aggblocks = ((N_NODES + 63) / 64) * NSH;
    int gemmblocks = N_NODES / TROWS;               // 625
    k_agg<<<aggblocks, 256, 0, stream>>>(bufA, rowptr, cs16, bufB);
    k_gemm<<<gemmblocks, 256, 0, stream>>>(bufB, W1, b1, bufB, N_NODES, 1, dinv,
                                           nullptr, nullptr, nullptr, nullptr);
    k_agg<<<aggblocks, 256, 0, stream>>>(bufB, rowptr, cs16, bufA);
    k_gemm<<<gemmblocks, 256, 0, stream>>>(bufA, W2, b2, bufA, N_NODES, 1, dinv,
                                           nullptr, nullptr, nullptr, nullptr);
    k_agg<<<aggblocks, 256, 0, stream>>>(bufA, rowptr, cs16, bufB);
    k_gemm<<<gemmblocks, 256, 0, stream>>>(bufB, W3, b3, nullptr, N_NODES, 0, nullptr,
                                           pw, pb, out, colsum);

    k_value<<<1, 128, 0, stream>>>(colsum, vw, vb, out + N_NODES);
}

// Round 26
// 283.275 us; speedup vs baseline: 1.0077x; 1.0077x over previous
//
#include <hip/hip_runtime.h>

// GCN forward, MI355X. v26 — FINAL: exact v24 (283.4us, best verified).
// Plateau demonstrated: v20-v25 (gemm quarters/4x8/grid-782, degree-bucket
// agg x2, RQH=8) all neutral or regressed. Remaining gaps are stall/latency
// structure ~2x above LDS/L2 floors; breaking them needs inline-asm
// pipelining or bf16/MFMA (tolerance-risky) — negative expected value here.
// Journey: 578 (v4 naive) -> 283.4: reg-tiled fp32 gemm + fused heads/scaling
// + panelized XCD-local gathers + atomic-free packed-u16 LDS CSR build +
// sentinel-padded 8-wide agg + u16 indices + occupancy-tuned chunk kernels.

#define N_NODES 50000
#define N_EDGES 800000
#define D 128
#define NSH 8
#define PROWS (N_NODES + 8)
#define PANEL ((size_t)PROWS * 16)
#define NC 64
#define CSZ (N_EDGES / NC)
#define NW (N_NODES / 2)
#define RQH 4
#define NWQ (NW / RQH)
#define CS_CAP (N_EDGES + 8 * N_NODES)
#define TROWS 80

// ---------------- CSR build (no global atomics) ----------------

__global__ __launch_bounds__(512) void k_hist3(const int* __restrict__ src, const int* __restrict__ dst,
                                               unsigned* __restrict__ ghd16, unsigned* __restrict__ ghs16) {
    __shared__ unsigned h[NWQ];         // 25 KB
    const int rq  = blockIdx.x & 3;
    const int arr = (blockIdx.x >> 2) & 1;
    const int c   = blockIdx.x >> 3;
    const int wbase = rq * NWQ;
    const int nbase = wbase * 2;
    const int t = threadIdx.x;
    for (int i = t; i < NWQ; i += 512) h[i] = 0u;
    __syncthreads();
    const int* __restrict__ col = arr ? src : dst;
    const int e0 = c * CSZ, e1 = e0 + CSZ;
    for (int e = e0 + t; e < e1; e += 512) {
        unsigned loc = (unsigned)(col[e] - nbase);
        if (loc < 2u * NWQ) atomicAdd(&h[loc >> 1], 1u << ((loc & 1) << 4));
    }
    __syncthreads();
    unsigned* __restrict__ outp = (arr ? ghs16 : ghd16) + (size_t)c * NW + wbase;
    for (int i = t; i < NWQ; i += 512) outp[i] = h[i];
}

__global__ __launch_bounds__(256) void k_merge3(unsigned* __restrict__ ghd16, const unsigned* __restrict__ ghs16,
                                                int* __restrict__ rowcnt, int* __restrict__ rowtrue,
                                                float* __restrict__ dinv) {
    int w = blockIdx.x * 256 + threadIdx.x;
    if (w >= NW) return;
    unsigned runlo = 0, runhi = 0;
#pragma unroll
    for (int c = 0; c < NC; c++) {
        unsigned v = ghd16[(size_t)c * NW + w];
        ghd16[(size_t)c * NW + w] = runlo | (runhi << 16);
        runlo += v & 0xffffu; runhi += v >> 16;
    }
    rowtrue[2 * w]     = (int)runlo;
    rowtrue[2 * w + 1] = (int)runhi;
    rowcnt[2 * w]      = (int)((runlo + 7u) & ~7u);
    rowcnt[2 * w + 1]  = (int)((runhi + 7u) & ~7u);
    unsigned dlo = 0, dhi = 0;
#pragma unroll
    for (int c = 0; c < NC; c++) {
        unsigned v = ghs16[(size_t)c * NW + w];
        dlo += v & 0xffffu; dhi += v >> 16;
    }
    dinv[2 * w]     = 1.0f / (float)(dlo > 1u ? dlo : 1u);
    dinv[2 * w + 1] = 1.0f / (float)(dhi > 1u ? dhi : 1u);
}

__global__ __launch_bounds__(1024) void k_scan1(const int* __restrict__ cnt, int* __restrict__ excl,
                                                int* __restrict__ blocksum, int n) {
    __shared__ int wsum[16];
    int i = blockIdx.x * 1024 + threadIdx.x;
    int v = (i < n) ? cnt[i] : 0;
    int lane = threadIdx.x & 63, wid = threadIdx.x >> 6;
    int x = v;
#pragma unroll
    for (int off = 1; off < 64; off <<= 1) {
        int y = __shfl_up(x, off, 64);
        if (lane >= off) x += y;
    }
    if (lane == 63) wsum[wid] = x;
    __syncthreads();
    if (threadIdx.x == 0) {
        int run = 0;
        for (int w = 0; w < 16; w++) { int t = wsum[w]; wsum[w] = run; run += t; }
        blocksum[blockIdx.x] = run;
    }
    __syncthreads();
    if (i < n) excl[i] = (x - v) + wsum[wid];
}

__global__ void k_scan2(const int* __restrict__ blocksum, int* __restrict__ blockoff,
                        int* __restrict__ rowptr_last, int nblk) {
    if (threadIdx.x == 0) {
        int run = 0;
        for (int b = 0; b < nblk; b++) { int t = blocksum[b]; blockoff[b] = run; run += t; }
        rowptr_last[0] = run;
    }
}

__global__ __launch_bounds__(1024) void k_scan3(int* __restrict__ excl, const int* __restrict__ blockoff, int n) {
    int i = blockIdx.x * 1024 + threadIdx.x;
    if (i < n) excl[i] += blockoff[blockIdx.x];
}

__global__ __launch_bounds__(512) void k_fill3(const int* __restrict__ src, const int* __restrict__ dst,
                                               const int* __restrict__ rowptr, const unsigned* __restrict__ ghd16,
                                               unsigned short* __restrict__ cs16) {
    __shared__ unsigned cnt[NWQ];       // 25 KB
    const int rq = blockIdx.x & 3;
    const int c  = blockIdx.x >> 2;
    const int nbase = rq * NWQ * 2;
    const int t = threadIdx.x;
    for (int i = t; i < NWQ; i += 512) cnt[i] = 0u;
    __syncthreads();
    const unsigned* __restrict__ basep = ghd16 + (size_t)c * NW;
    const int e0 = c * CSZ, e1 = e0 + CSZ;
    for (int e = e0 + t; e < e1; e += 512) {
        int d = dst[e];
        unsigned loc = (unsigned)(d - nbase);
        if (loc < 2u * NWQ) {
            int sh = (loc & 1) << 4;
            unsigned old = atomicAdd(&cnt[loc >> 1], 1u << sh);
            int p = (int)((old >> sh) & 0xffffu);
            int base = (int)((basep[d >> 1] >> ((d & 1) << 4)) & 0xffffu);
            cs16[rowptr[d] + base + p] = (unsigned short)src[e];
        }
    }
}

__global__ __launch_bounds__(256) void k_pad(const int* __restrict__ rowptr, const int* __restrict__ rowtrue,
                                             unsigned short* __restrict__ cs16,
                                             float* __restrict__ bufA, float* __restrict__ bufB) {
    int n = blockIdx.x * 256 + threadIdx.x;
    if (n < N_NODES) {
        int e0 = rowptr[n] + rowtrue[n], e1 = rowptr[n + 1];
        for (int e = e0; e < e1; e++) cs16[e] = (unsigned short)N_NODES;
    }
    if (blockIdx.x == 0) {
        int t = threadIdx.x;
        float* b = (t & 128) ? bufB : bufA;
        int p = (t >> 4) & 7, cc = t & 15;
        b[(size_t)p * PANEL + (size_t)N_NODES * 16 + cc] = 0.f;
    }
}

// ---------------- panelize ----------------

__global__ __launch_bounds__(256) void k_panelize(const float* __restrict__ in, const float* __restrict__ dinv,
                                                  float* __restrict__ outp) {
    int tid = blockIdx.x * 256 + threadIdx.x;
    if (tid >= N_NODES * 32) return;
    int p = tid / (N_NODES * 4);
    int r = tid - p * (N_NODES * 4);
    int node = r >> 2, qq = r & 3;
    float w = dinv[node];
    float4 v = *reinterpret_cast<const float4*>(&in[(size_t)node * D + p * 16 + qq * 4]);
    v.x *= w; v.y *= w; v.z *= w; v.w *= w;
    *reinterpret_cast<float4*>(&outp[(size_t)p * PANEL + (size_t)node * 16 + qq * 4]) = v;
}

// ---------------- SpMM aggregation (v16 proven: natural order) ----------------

__global__ __launch_bounds__(256) void k_agg(const float* __restrict__ hp,
                                             const int* __restrict__ rp, const unsigned short* __restrict__ cs16,
                                             float* __restrict__ outp) {
    const int l4 = threadIdx.x & 3;
    const int grp = threadIdx.x >> 2;
    const int slice = blockIdx.x & (NSH - 1);
    const int node = (blockIdx.x >> 3) * 64 + grp;
    if (node >= N_NODES) return;
    const float* __restrict__ pan = hp + (size_t)slice * PANEL + l4 * 4;
    int s0 = rp[node], s1 = rp[node + 1];
    float4 acc = {0.f, 0.f, 0.f, 0.f};
    for (int e = s0; e < s1; e += 8) {
        int4 r = *reinterpret_cast<const int4*>(&cs16[e]);
        int i0 = r.x & 0xffff, i1 = (r.x >> 16) & 0xffff;
        int i2 = r.y & 0xffff, i3 = (r.y >> 16) & 0xffff;
        int i4 = r.z & 0xffff, i5 = (r.z >> 16) & 0xffff;
        int i6 = r.w & 0xffff, i7 = (r.w >> 16) & 0xffff;
        float4 a0 = *reinterpret_cast<const float4*>(&pan[(size_t)i0 * 16]);
        float4 a1 = *reinterpret_cast<const float4*>(&pan[(size_t)i1 * 16]);
        float4 a2 = *reinterpret_cast<const float4*>(&pan[(size_t)i2 * 16]);
        float4 a3 = *reinterpret_cast<const float4*>(&pan[(size_t)i3 * 16]);
        float4 a4 = *reinterpret_cast<const float4*>(&pan[(size_t)i4 * 16]);
        float4 a5 = *reinterpret_cast<const float4*>(&pan[(size_t)i5 * 16]);
        float4 a6 = *reinterpret_cast<const float4*>(&pan[(size_t)i6 * 16]);
        float4 a7 = *reinterpret_cast<const float4*>(&pan[(size_t)i7 * 16]);
        acc.x += ((a0.x + a1.x) + (a2.x + a3.x)) + ((a4.x + a5.x) + (a6.x + a7.x));
        acc.y += ((a0.y + a1.y) + (a2.y + a3.y)) + ((a4.y + a5.y) + (a6.y + a7.y));
        acc.z += ((a0.z + a1.z) + (a2.z + a3.z)) + ((a4.z + a5.z) + (a6.z + a7.z));
        acc.w += ((a0.w + a1.w) + (a2.w + a3.w)) + ((a4.w + a5.w) + (a6.w + a7.w));
    }
    *reinterpret_cast<float4*>(&outp[(size_t)slice * PANEL + (size_t)node * 16 + l4 * 4]) = acc;
}

// ---------------- dense layer (v18/v19 proven: 80x128, 52KB, grid 625) ----------------

__global__ __launch_bounds__(256, 3) void k_gemm(const float* __restrict__ in, const float* __restrict__ W,
                                                 const float* __restrict__ bias, float* __restrict__ out,
                                                 int nrows, int relu,
                                                 const float* __restrict__ dscale,
                                                 const float* __restrict__ pw, const float* __restrict__ pb,
                                                 float* __restrict__ pi_out, float* __restrict__ colsum) {
    __shared__ float wl[64 * D];     // 32 KB: current W k-half
    __shared__ float at[64 * TROWS]; // 20 KB
    int t = threadIdx.x;
    const int head = (pw != nullptr);
    const int tx = t & 15;
    const int ro = t >> 4;
    const int row0 = blockIdx.x * TROWS;
    float4 bv1 = reinterpret_cast<const float4*>(bias)[tx];
    float4 bv2 = reinterpret_cast<const float4*>(bias)[16 + tx];
    float4 pw1 = head ? reinterpret_cast<const float4*>(pw)[tx]      : float4{0, 0, 0, 0};
    float4 pw2 = head ? reinterpret_cast<const float4*>(pw)[16 + tx] : float4{0, 0, 0, 0};
    float pb0 = head ? pb[0] : 0.f;
    float4 cs1 = {0, 0, 0, 0}, cs2 = {0, 0, 0, 0};

    int sidx[5], skb[5];
#pragma unroll
    for (int j = 0; j < 5; j++) {
        int i = t + j * 256;
        int r = i % TROWS;
        int pq = i / TROWS;
        sidx[j] = r;
        skb[j] = (pq & 3) * 4 + (pq >> 2) * 16;
    }

#define LOADA(va, h)                                                                   \
    _Pragma("unroll")                                                                  \
    for (int j = 0; j < 5; j++) {                                                      \
        int i = t + j * 256;                                                           \
        int pq = i / TROWS;                                                            \
        int p = (h) * 4 + (pq >> 2);                                                   \
        int c4 = pq & 3;                                                               \
        va[j] = *reinterpret_cast<const float4*>(                                      \
            &in[(size_t)p * PANEL + (size_t)(row0 + sidx[j]) * 16 + c4 * 4]);          \
    }

#define WRITEA(va)                                                                     \
    _Pragma("unroll")                                                                  \
    for (int j = 0; j < 5; j++) {                                                      \
        int kb = skb[j], r = sidx[j];                                                  \
        at[(kb + 0) * TROWS + r] = va[j].x; at[(kb + 1) * TROWS + r] = va[j].y;        \
        at[(kb + 2) * TROWS + r] = va[j].z; at[(kb + 3) * TROWS + r] = va[j].w;        \
    }

#define STAGEW(h)                                                                      \
    _Pragma("unroll")                                                                  \
    for (int j = 0; j < 8; j++) {                                                      \
        int i = t + j * 256;                                                           \
        reinterpret_cast<float4*>(wl)[i] =                                             \
            reinterpret_cast<const float4*>(W + (h) * 64 * D)[i];                      \
    }

#define KLOOP                                                                          \
    _Pragma("unroll 4")                                                                \
    for (int kk = 0; kk < 64; kk++) {                                                  \
        float4 a  = *reinterpret_cast<const float4*>(&at[kk * TROWS + ro * 5]);        \
        float  a4 = at[kk * TROWS + ro * 5 + 4];                                       \
        float4 w1 = *reinterpret_cast<const float4*>(&wl[kk * D + tx * 4]);            \
        float4 w2 = *reinterpret_cast<const float4*>(&wl[kk * D + 64 + tx * 4]);       \
        acc[0][0] += a.x * w1.x; acc[0][1] += a.x * w1.y; acc[0][2] += a.x * w1.z; acc[0][3] += a.x * w1.w; \
        acc[0][4] += a.x * w2.x; acc[0][5] += a.x * w2.y; acc[0][6] += a.x * w2.z; acc[0][7] += a.x * w2.w; \
        acc[1][0] += a.y * w1.x; acc[1][1] += a.y * w1.y; acc[1][2] += a.y * w1.z; acc[1][3] += a.y * w1.w; \
        acc[1][4] += a.y * w2.x; acc[1][5] += a.y * w2.y; acc[1][6] += a.y * w2.z; acc[1][7] += a.y * w2.w; \
        acc[2][0] += a.z * w1.x; acc[2][1] += a.z * w1.y; acc[2][2] += a.z * w1.z; acc[2][3] += a.z * w1.w; \
        acc[2][4] += a.z * w2.x; acc[2][5] += a.z * w2.y; acc[2][6] += a.z * w2.z; acc[2][7] += a.z * w2.w; \
        acc[3][0] += a.w * w1.x; acc[3][1] += a.w * w1.y; acc[3][2] += a.w * w1.z; acc[3][3] += a.w * w1.w; \
        acc[3][4] += a.w * w2.x; acc[3][5] += a.w * w2.y; acc[3][6] += a.w * w2.z; acc[3][7] += a.w * w2.w; \
        acc[4][0] += a4 * w1.x; acc[4][1] += a4 * w1.y; acc[4][2] += a4 * w1.z; acc[4][3] += a4 * w1.w;     \
        acc[4][4] += a4 * w2.x; acc[4][5] += a4 * w2.y; acc[4][6] += a4 * w2.z; acc[4][7] += a4 * w2.w;     \
    }

    float acc[5][8];
#pragma unroll
    for (int j = 0; j < 5; j++)
#pragma unroll
        for (int c = 0; c < 8; c++) acc[j][c] = 0.f;

    float4 va[5];
    LOADA(va, 0);
    STAGEW(0);
    WRITEA(va);
    __syncthreads();
    LOADA(va, 1);
    KLOOP;
    __syncthreads();
    WRITEA(va);
    STAGEW(1);
    __syncthreads();
    KLOOP;

#pragma unroll
    for (int j = 0; j < 5; j++) {
        int gr = row0 + ro * 5 + j;
        float4 o1, o2;
        o1.x = acc[j][0] + bv1.x; o1.y = acc[j][1] + bv1.y;
        o1.z = acc[j][2] + bv1.z; o1.w = acc[j][3] + bv1.w;
        o2.x = acc[j][4] + bv2.x; o2.y = acc[j][5] + bv2.y;
        o2.z = acc[j][6] + bv2.z; o2.w = acc[j][7] + bv2.w;
        if (relu) {
            o1.x = fmaxf(o1.x, 0.f); o1.y = fmaxf(o1.y, 0.f);
            o1.z = fmaxf(o1.z, 0.f); o1.w = fmaxf(o1.w, 0.f);
            o2.x = fmaxf(o2.x, 0.f); o2.y = fmaxf(o2.y, 0.f);
            o2.z = fmaxf(o2.z, 0.f); o2.w = fmaxf(o2.w, 0.f);
        }
        if (head) {
            cs1.x += o1.x; cs1.y += o1.y; cs1.z += o1.z; cs1.w += o1.w;
            cs2.x += o2.x; cs2.y += o2.y; cs2.z += o2.z; cs2.w += o2.w;
            float pr = o1.x * pw1.x + o1.y * pw1.y + o1.z * pw1.z + o1.w * pw1.w
                     + o2.x * pw2.x + o2.y * pw2.y + o2.z * pw2.z + o2.w * pw2.w;
#pragma unroll
            for (int m = 8; m > 0; m >>= 1) pr += __shfl_xor(pr, m, 16);
            if (tx == 0) pi_out[gr] = pr + pb0;
        } else {
            if (dscale) {
                float w = dscale[gr];
                o1.x *= w; o1.y *= w; o1.z *= w; o1.w *= w;
                o2.x *= w; o2.y *= w; o2.z *= w; o2.w *= w;
            }
            size_t base1 = (size_t)(tx >> 2) * PANEL + (size_t)gr * 16 + (tx & 3) * 4;
            *reinterpret_cast<float4*>(&out[base1]) = o1;
            *reinterpret_cast<float4*>(&out[base1 + 4 * PANEL]) = o2;
        }
    }

    if (head) {
        __syncthreads();
        float* csl = at;
        if (t < D) csl[t] = 0.f;
        __syncthreads();
        atomicAdd(&csl[tx * 4 + 0], cs1.x);
        atomicAdd(&csl[tx * 4 + 1], cs1.y);
        atomicAdd(&csl[tx * 4 + 2], cs1.z);
        atomicAdd(&csl[tx * 4 + 3], cs1.w);
        atomicAdd(&csl[64 + tx * 4 + 0], cs2.x);
        atomicAdd(&csl[64 + tx * 4 + 1], cs2.y);
        atomicAdd(&csl[64 + tx * 4 + 2], cs2.z);
        atomicAdd(&csl[64 + tx * 4 + 3], cs2.w);
        __syncthreads();
        if (t < D) atomicAdd(&colsum[t], csl[t]);
    }
#undef LOADA
#undef WRITEA
#undef STAGEW
#undef KLOOP
}

// ---------------- value head ----------------

__global__ __launch_bounds__(128) void k_value(const float* __restrict__ colsum, const float* __restrict__ vw,
                                               const float* __restrict__ vb, float* __restrict__ out) {
    __shared__ float red[128];
    int t = threadIdx.x;
    red[t] = (colsum[t] * (1.0f / (float)N_NODES)) * vw[t];
    __syncthreads();
    for (int s = 64; s > 0; s >>= 1) {
        if (t < s) red[t] += red[t + s];
        __syncthreads();
    }
    if (t == 0) out[0] = red[0] + vb[0];
}

__global__ __launch_bounds__(64) void k_ws_too_small(float* __restrict__ out, int n) {
    int i = blockIdx.x * 64 + threadIdx.x;
    if (i < n) out[i] = -1e30f;
}

// ---------------- launch ----------------

extern "C" void kernel_launch(void* const* d_in, const int* in_sizes, int n_in,
                              void* d_out, int out_size, void* d_ws, size_t ws_size,
                              hipStream_t stream) {
    const float* features = (const float*)d_in[0];
    const int*   src      = (const int*)d_in[1];
    const int*   dst      = (const int*)d_in[2];
    const float* W1 = (const float*)d_in[3];
    const float* b1 = (const float*)d_in[4];
    const float* W2 = (const float*)d_in[5];
    const float* b2 = (const float*)d_in[6];
    const float* W3 = (const float*)d_in[7];
    const float* b3 = (const float*)d_in[8];
    const float* pw = (const float*)d_in[9];
    const float* pb = (const float*)d_in[10];
    const float* vw = (const float*)d_in[11];
    const float* vb = (const float*)d_in[12];
    float* out = (float*)d_out;

    char* ws = (char*)d_ws;
    size_t off = 0;
    auto alloc = [&](size_t bytes) -> char* {
        char* p = ws + off;
        off += (bytes + 255) & ~(size_t)255;
        return p;
    };
    float* dinv     = (float*)alloc((size_t)N_NODES * 4);
    int*   rowptr   = (int*)alloc((size_t)(N_NODES + 1) * 4);
    int*   rowcnt   = (int*)alloc((size_t)N_NODES * 4);
    int*   rowtrue  = (int*)alloc((size_t)N_NODES * 4);
    int*   blocksum = (int*)alloc(64 * 4);
    int*   blockoff = (int*)alloc(64 * 4);
    float* colsum   = (float*)alloc(D * 4);
    unsigned short* cs16 = (unsigned short*)alloc((size_t)CS_CAP * 2);
    float* bufA     = (float*)alloc((size_t)NSH * PANEL * 4);
    float* bufB     = (float*)alloc((size_t)NSH * PANEL * 4);

    unsigned* ghd16 = (unsigned*)bufB;
    unsigned* ghs16 = ghd16 + (size_t)NC * NW;

    if (off > ws_size) {
        k_ws_too_small<<<(out_size + 63) / 64, 64, 0, stream>>>(out, out_size);
        return;
    }

    hipMemsetAsync(colsum, 0, (size_t)D * 4, stream);

    k_hist3<<<NC * 2 * RQH, 512, 0, stream>>>(src, dst, ghd16, ghs16);
    k_merge3<<<(NW + 255) / 256, 256, 0, stream>>>(ghd16, ghs16, rowcnt, rowtrue, dinv);

    int nblk = (N_NODES + 1023) / 1024;
    k_scan1<<<nblk, 1024, 0, stream>>>(rowcnt, rowptr, blocksum, N_NODES);
    k_scan2<<<1, 64, 0, stream>>>(blocksum, blockoff, rowptr + N_NODES, nblk);
    k_scan3<<<nblk, 1024, 0, stream>>>(rowptr, blockoff, N_NODES);
    k_fill3<<<NC * RQH, 512, 0, stream>>>(src, dst, rowptr, ghd16, cs16);
    k_pad<<<(N_NODES + 255) / 256, 256, 0, stream>>>(rowptr, rowtrue, cs16, bufA, bufB);

    k_panelize<<<(N_NODES * 32 + 255) / 256, 256, 0, stream>>>(features, dinv, bufA);

    int aggblocks = ((N_NODES + 63) / 64) * NSH;
    int gemmblocks = N_NODES / TROWS;               // 625
    k_agg<<<aggblocks, 256, 0, stream>>>(bufA, rowptr, cs16, bufB);
    k_gemm<<<gemmblocks, 256, 0, stream>>>(bufB, W1, b1, bufB, N_NODES, 1, dinv,
                                           nullptr, nullptr, nullptr, nullptr);
    k_agg<<<aggblocks, 256, 0, stream>>>(bufB, rowptr, cs16, bufA);
    k_gemm<<<gemmblocks, 256, 0, stream>>>(bufA, W2, b2, bufA, N_NODES, 1, dinv,
                                           nullptr, nullptr, nullptr, nullptr);
    k_agg<<<aggblocks, 256, 0, stream>>>(bufA, rowptr, cs16, bufB);
    k_gemm<<<gemmblocks, 256, 0, stream>>>(bufB, W3, b3, nullptr, N_NODES, 0, nullptr,
                                           pw, pb, out, colsum);

    k_value<<<1, 128, 0, stream>>>(colsum, vw, vb, out + N_NODES);
}